// Round 2
// baseline (1197.092 us; speedup 1.0000x reference)
//
#include <hip/hip_runtime.h>
#include <hip/hip_bf16.h>

// Problem constants
#define M_TOK 16384
#define N_OUT 6144
#define K_IN  4096
#define SBLK  128   // scale block
#define NT    (K_IN / 64)   // 64 K-tiles of BK=64

typedef __bf16 bf16x8 __attribute__((ext_vector_type(8)));
typedef float  f32x4  __attribute__((ext_vector_type(4)));

// fp32 -> bf16 round-to-nearest-even (bit trick; inputs are normal floats)
__device__ __forceinline__ unsigned short f2bf(float f) {
    unsigned int u = __builtin_bit_cast(unsigned int, f);
    u += 0x7fffu + ((u >> 16) & 1u);
    return (unsigned short)(u >> 16);
}

// async global->LDS, 16 B per lane, LDS dest = wave-uniform base + lane*16
__device__ __forceinline__ void async16(const void* g, void* l) {
    __builtin_amdgcn_global_load_lds(
        (const __attribute__((address_space(1))) unsigned int*)g,
        (__attribute__((address_space(3))) unsigned int*)l,
        16, 0, 0);
}

// ---- prep kernel 1: x fp32 -> bf16 (row-major [M, K], K-contiguous) ----
__global__ __launch_bounds__(256) void cvt_x_kernel(
        const float* __restrict__ x, unsigned short* __restrict__ out) {
    int i = blockIdx.x * 256 + threadIdx.x;          // float4 index
    float4 v = ((const float4*)x)[i];
    ushort4 o;
    o.x = f2bf(v.x); o.y = f2bf(v.y); o.z = f2bf(v.z); o.w = f2bf(v.w);
    ((ushort4*)out)[i] = o;
}

// ---- prep kernel 2: w fp32 * blockscale -> bf16 ([N, K], K-contiguous) ----
__global__ __launch_bounds__(256) void cvt_w_kernel(
        const float* __restrict__ w, const float* __restrict__ s,
        unsigned short* __restrict__ out) {
    int i = blockIdx.x * 256 + threadIdx.x;          // float4 index
    int e = i << 2;                                  // element index
    int o = e >> 12;                                 // / K_IN
    int k = e & (K_IN - 1);
    float scale = s[(o >> 7) * (K_IN / SBLK) + (k >> 7)];
    float4 v = ((const float4*)w)[i];
    ushort4 r;
    r.x = f2bf(v.x * scale); r.y = f2bf(v.y * scale);
    r.z = f2bf(v.z * scale); r.w = f2bf(v.w * scale);
    ((ushort4*)out)[i] = r;
}

// ======================================================================
// GEMM: C[M,N] = A[M,K] * B[N,K]^T, bf16 in, fp32 out.
// 256x256 tile, BK=64, 512 threads = 8 waves (2M x 4N), 8-phase schedule
// (m194-m201 template): per phase {ds_read subtile | stage 1 half-tile via
// global_load_lds -> bar -> lgkmcnt(0) -> 16 MFMA -> bar}, counted vmcnt(4)
// once per K-tile, st_16x32 LDS swizzle, setprio around MFMA cluster.
//
// LDS map (128 KiB): buffer c (0/1) at c*65536; slots (16384 B each):
//   0 = A-half0 (tile rows   0-127), 1 = A-half1 (rows 128-255),
//   2 = B-half0 (cols 0-127), 3 = B-half1 (cols 128-255).
// Slot = 2 k-planes (8192 B) x [128 rows][32 bf16]; physical byte =
//   L ^ (((L>>9)&1)<<5)  (st_16x32 swizzle, involution).
// global_load_lds writes LINEAR (base + lane*16); the swizzle is applied by
// inverse-permuting the per-lane GLOBAL source address (m173 / rule 21).
//
// Staging schedule (write-after-read safe; every slot's re-stage is issued
// after the bar2 of the phase that last read it):
//   ph0(t): stage A0(t+1)   ph1(t): stage A1(t+1)
//   ph2(t): stage B0(t+2)   ph3(t): stage B1(t+2); boundary wait; bar
//
// vmcnt ledger (per wave, 2 loads per STAGE):
//   steady state: at ph3(t) boundary, newest 4 = B0/B1(t+2) -> vmcnt(4)
//     guarantees A0/A1(t+1) and B0/B1(t+1) landed before tile t+1 reads.
//   TAIL (t = NT-2): B-stages are guarded off, so the newest 4 outstanding
//     are A0/A1(NT-1) themselves -> vmcnt(4) would NOT wait for them (this
//     was the round-1 race). The last two K-tiles are peeled with a full
//     vmcnt(0) drain at the boundary instead.
// ======================================================================

#define BAR()     __builtin_amdgcn_s_barrier()
#define SCHED0()  __builtin_amdgcn_sched_barrier(0)
#define PRIO1()   __builtin_amdgcn_s_setprio(1)
#define PRIO0()   __builtin_amdgcn_s_setprio(0)
#define WAIT_LGKM0() asm volatile("s_waitcnt lgkmcnt(0)" ::: "memory")
#define WAIT_VM4()   asm volatile("s_waitcnt vmcnt(4)"   ::: "memory")
#define WAIT_VM0()   asm volatile("s_waitcnt vmcnt(0)"   ::: "memory")

__global__ __launch_bounds__(512, 2) void gemm256_kernel(
        const unsigned short* __restrict__ A,
        const unsigned short* __restrict__ B,
        float* __restrict__ C) {
    __shared__ __attribute__((aligned(1024))) unsigned char ldsb[131072];

    const int tid  = threadIdx.x;
    const int wave = tid >> 6;
    const int lane = tid & 63;
    const int bn   = blockIdx.x;   // 0..23
    const int bm   = blockIdx.y;   // 0..63
    const int wm   = wave >> 2;    // 0..1  (M half)
    const int wn   = wave & 3;     // 0..3  (N quarter)
    const int lr   = lane & 15;
    const int lgp  = lane >> 4;

    // per-lane swizzled ds-read base offset within a slot (bytes).
    // logical L = ksub*8192 + row*64 + lgp*16; XOR bit = (row>>3)&1 = (lr>>3)&1
    // for all 16-aligned frag bases, so one base serves every fragment.
    const int aoff = (lr * 64 + lgp * 16) ^ (((lr >> 3) & 1) << 5);

    // LDS read-base pointers per buffer (A: own M-half; B: own N-half + 64-row sub)
    const unsigned char* pa[2] = {
        ldsb +          wm * 16384,
        ldsb + 65536 +  wm * 16384 };
    const unsigned char* pb[2] = {
        ldsb +          (2 + (wn >> 1)) * 16384 + (wn & 1) * 4096,
        ldsb + 65536 +  (2 + (wn >> 1)) * 16384 + (wn & 1) * 4096 };

    // staging precompute: subtiles s0,s1 (1024 B each) of a 16 KiB slot.
    // physical byte = s*1024 + lane*16; inverse-swizzled logical:
    const int s0   = wave * 2, s1 = s0 + 1;
    const int lswz = (lane * 16) ^ (lane & 32);       // L within subtile
    const int r_in = lswz >> 6;                       // row within 16-row group
    const int kel  = (lswz & 63) >> 1;                // element within 32-k plane row
    const int goff0 = ((s0 & 7) * 16 + r_in) * K_IN + (s0 >> 3) * 32 + kel;
    const int goff1 = ((s1 & 7) * 16 + r_in) * K_IN + (s1 >> 3) * 32 + kel;
    const int ldso0 = s0 * 1024, ldso1 = s1 * 1024;   // wave-uniform

    const unsigned short* gA = A + (size_t)bm * 256 * K_IN;
    const unsigned short* gB = B + (size_t)bn * 256 * K_IN;
    const unsigned short* gA0p0 = gA + goff0;
    const unsigned short* gA0p1 = gA + goff1;
    const unsigned short* gA1p0 = gA0p0 + (size_t)128 * K_IN;
    const unsigned short* gA1p1 = gA0p1 + (size_t)128 * K_IN;
    const unsigned short* gB0p0 = gB + goff0;
    const unsigned short* gB0p1 = gB + goff1;
    const unsigned short* gB1p0 = gB0p0 + (size_t)128 * K_IN;
    const unsigned short* gB1p1 = gB0p1 + (size_t)128 * K_IN;

#define STAGE(BUF, SLOT, PP0, PP1, K0) do {                                   \
        async16(PP0 + (K0), ldsb + (BUF) * 65536 + (SLOT) * 16384 + ldso0);   \
        async16(PP1 + (K0), ldsb + (BUF) * 65536 + (SLOT) * 16384 + ldso1);   \
    } while (0)

    f32x4 acc[8][4];
#pragma unroll
    for (int mi = 0; mi < 8; ++mi)
#pragma unroll
        for (int ni = 0; ni < 4; ++ni)
            acc[mi][ni] = {0.f, 0.f, 0.f, 0.f};

    bf16x8 a[4][2];   // 4 M-frags (of current quadrant) x 2 k-substeps
    bf16x8 b[4][2];   // 4 N-frags x 2 k-substeps

#define RD_A4(FB, P) do {                                                     \
        _Pragma("unroll") for (int f = 0; f < 4; ++f) {                       \
            a[f][0] = *(const bf16x8*)((P) + aoff + ((FB) + f) * 1024);       \
            a[f][1] = *(const bf16x8*)((P) + aoff + ((FB) + f) * 1024 + 8192);\
        } } while (0)

#define RD_B2(F0, P) do {                                                     \
        _Pragma("unroll") for (int f = 0; f < 2; ++f) {                       \
            b[(F0)+f][0] = *(const bf16x8*)((P) + aoff + ((F0)+f) * 1024);       \
            b[(F0)+f][1] = *(const bf16x8*)((P) + aoff + ((F0)+f) * 1024 + 8192);\
        } } while (0)

#define MFMA_PH(MB, NB) do {                                                  \
        _Pragma("unroll") for (int mi = 0; mi < 4; ++mi)                      \
        _Pragma("unroll") for (int ni = 0; ni < 2; ++ni)                      \
        _Pragma("unroll") for (int kk = 0; kk < 2; ++kk)                      \
            acc[(MB)+mi][(NB)+ni] = __builtin_amdgcn_mfma_f32_16x16x32_bf16(  \
                a[mi][kk], b[(NB)+ni][kk], acc[(MB)+mi][(NB)+ni], 0, 0, 0);   \
    } while (0)

// KTILE: WAITB = the boundary wait at end of ph3 (WAIT_VM4 in steady state,
// WAIT_VM0 for the peeled tail tiles where the B-stage guards are off).
#define KTILE(T, CBUF, WAITB) do {                                            \
        /* ---- ph0: A frags 0-3 + B frags 0-1; stage A0(t+1) ---- */         \
        RD_A4(0, pa[CBUF]); RD_B2(0, pb[CBUF]);                               \
        if ((T) + 1 < NT) STAGE(1 - (CBUF), 0, gA0p0, gA0p1, ((T) + 1) * 64); \
        BAR(); WAIT_LGKM0(); SCHED0();                                        \
        PRIO1(); MFMA_PH(0, 0); PRIO0();                                      \
        BAR(); SCHED0();                                                      \
        /* ---- ph1: B frags 2-3; stage A1(t+1) ---- */                       \
        RD_B2(2, pb[CBUF]);                                                   \
        if ((T) + 1 < NT) STAGE(1 - (CBUF), 1, gA1p0, gA1p1, ((T) + 1) * 64); \
        BAR(); WAIT_LGKM0(); SCHED0();                                        \
        PRIO1(); MFMA_PH(0, 2); PRIO0();                                      \
        BAR(); SCHED0();                                                      \
        /* ---- ph2: A frags 4-7; stage B0(t+2) ---- */                       \
        RD_A4(4, pa[CBUF]);                                                   \
        if ((T) + 2 < NT) STAGE((CBUF), 2, gB0p0, gB0p1, ((T) + 2) * 64);     \
        BAR(); WAIT_LGKM0(); SCHED0();                                        \
        PRIO1(); MFMA_PH(4, 0); PRIO0();                                      \
        BAR(); SCHED0();                                                      \
        /* ---- ph3: stage B1(t+2); boundary wait ---- */                     \
        if ((T) + 2 < NT) STAGE((CBUF), 3, gB1p0, gB1p1, ((T) + 2) * 64);     \
        BAR(); WAIT_LGKM0(); SCHED0();                                        \
        PRIO1(); MFMA_PH(4, 2); PRIO0();                                      \
        WAITB(); BAR(); SCHED0();                                             \
    } while (0)

    // prologue: issue order = B0(0),B1(0),A0(0),A1(0),B0(1),B1(1) so the
    // 4 newest loads at the first boundary are B0(1),B1(1) (allowed in flight)
    STAGE(0, 2, gB0p0, gB0p1, 0);
    STAGE(0, 3, gB1p0, gB1p1, 0);
    STAGE(0, 0, gA0p0, gA0p1, 0);
    STAGE(0, 1, gA1p0, gA1p1, 0);
    STAGE(1, 2, gB0p0, gB0p1, 64);
    STAGE(1, 3, gB1p0, gB1p1, 64);
    WAIT_VM4(); BAR(); SCHED0();

    // main loop: tiles 0 .. NT-3 (steady state, counted vmcnt(4) boundaries)
#pragma unroll 1
    for (int t = 0; t < NT - 2; t += 2) {
        KTILE(t, 0, WAIT_VM4);
        KTILE(t + 1, 1, WAIT_VM4);
    }
    // peeled tail: tile NT-2 still stages A(NT-1) but no B-stages follow to
    // push them past the vmcnt(4) threshold -> full drain before tile NT-1.
    KTILE(NT - 2, 0, WAIT_VM0);
    KTILE(NT - 1, 1, WAIT_VM0);

    // epilogue: C/D layout col = lane&15, row = (lane>>4)*4 + reg (m89/m91)
    const int r0 = bm * 256 + wm * 128;
    const int c0 = bn * 256 + wn * 64;
#pragma unroll
    for (int mi = 0; mi < 8; ++mi) {
#pragma unroll
        for (int ni = 0; ni < 4; ++ni) {
            int col  = c0 + ni * 16 + lr;
            int rowb = r0 + mi * 16 + lgp * 4;
#pragma unroll
            for (int r = 0; r < 4; ++r)
                C[(size_t)(rowb + r) * N_OUT + col] = acc[mi][ni][r];
        }
    }
}

extern "C" void kernel_launch(void* const* d_in, const int* in_sizes, int n_in,
                              void* d_out, int out_size, void* d_ws, size_t ws_size,
                              hipStream_t stream) {
    const float* x = (const float*)d_in[0];                 // [16384, 4096]
    const float* w = (const float*)d_in[1];                 // [6144, 4096]
    const float* s = (const float*)d_in[2];                 // [48, 32]
    float* out = (float*)d_out;                             // [16384, 6144]

    unsigned short* xb = (unsigned short*)d_ws;             // 134 MB
    unsigned short* wb = xb + (size_t)M_TOK * K_IN;         // +50 MB

    // x: 67108864 elems / 4 = 16777216 float4s / 256 = 65536 blocks
    cvt_x_kernel<<<65536, 256, 0, stream>>>(x, xb);
    // w: 25165824 elems / 4 = 6291456 float4s / 256 = 24576 blocks
    cvt_w_kernel<<<24576, 256, 0, stream>>>(w, s, wb);

    dim3 grid(N_OUT / 256, M_TOK / 256);                    // 24 x 64
    gemm256_kernel<<<grid, 512, 0, stream>>>(xb, wb, out);
}